// Round 1
// baseline (23.708 us; speedup 1.0000x reference)
//
#include <hip/hip_runtime.h>
#include <math.h>

// NN-MSE (one-directional Chamfer) loss:
//   src_t[b,n,:] = R[b] @ coord[b,n,:] + t[b]
//   nn_d2[b,n]   = min_m |src_t[b,n,:] - tgt[b,m,:]|^2
//   loss         = mean_b mean_n nn_d2
//
// B=16, S=2048 -> 512 blocks x 256 threads.
// Each block: one segment b, 64 source points; target loop split across the
// 4 waves (each thread scans S/4 targets from an LDS-staged float4 tile).

#define SRC_PER_BLOCK 64
#define NQ 4
#define THREADS (SRC_PER_BLOCK * NQ)

__global__ __launch_bounds__(THREADS)
void nn_partial_kernel(const float* __restrict__ coord,
                       const float* __restrict__ coord_t,
                       const float* __restrict__ Rm,
                       const float* __restrict__ tv,
                       float* __restrict__ ws,
                       int S, int chunksPerSeg) {
    extern __shared__ char smem_raw[];
    float4* tgts = (float4*)smem_raw;                 // S * 16 bytes
    float*  part = (float*)(smem_raw + (size_t)S * 16); // THREADS floats

    const int bid   = blockIdx.x;
    const int b     = bid / chunksPerSeg;
    const int chunk = bid - b * chunksPerSeg;
    const int tid   = threadIdx.x;

    // ---- stage target segment into LDS (padded float4) ----
    const float* tb = coord_t + (size_t)b * S * 3;
    for (int m = tid; m < S; m += THREADS) {
        tgts[m] = make_float4(tb[3*m + 0], tb[3*m + 1], tb[3*m + 2], 0.0f);
    }

    // ---- per-thread source point, rigid transform ----
    const int s = tid & (SRC_PER_BLOCK - 1);   // source point within chunk
    const int q = tid >> 6;                    // which quarter of targets
    const int n = chunk * SRC_PER_BLOCK + s;

    const float* Rb = Rm + (size_t)b * 9;
    const float r00 = Rb[0], r01 = Rb[1], r02 = Rb[2];
    const float r10 = Rb[3], r11 = Rb[4], r12 = Rb[5];
    const float r20 = Rb[6], r21 = Rb[7], r22 = Rb[8];
    const float t0 = tv[b*3 + 0], t1 = tv[b*3 + 1], t2 = tv[b*3 + 2];

    const float* sp = coord + ((size_t)b * S + n) * 3;
    const float x = sp[0], y = sp[1], z = sp[2];
    const float sx = r00*x + r01*y + r02*z + t0;
    const float sy = r10*x + r11*y + r12*z + t1;
    const float sz = r20*x + r21*y + r22*z + t2;

    __syncthreads();

    // ---- scan this wave's quarter of targets; LDS broadcast reads ----
    const int mPer = S / NQ;
    const int m0 = q * mPer;
    const int m1 = m0 + mPer;
    float best = 3.0e38f;
    #pragma unroll 8
    for (int m = m0; m < m1; ++m) {
        float4 p = tgts[m];
        float dx = sx - p.x;
        float dy = sy - p.y;
        float dz = sz - p.z;
        float d2 = dx*dx + dy*dy + dz*dz;
        best = fminf(best, d2);
    }

    // ---- combine quarters (min), then sum over the 64 source points ----
    part[tid] = best;
    __syncthreads();
    if (tid < SRC_PER_BLOCK) {
        float mn = part[tid];
        #pragma unroll
        for (int qq = 1; qq < NQ; ++qq)
            mn = fminf(mn, part[qq * SRC_PER_BLOCK + tid]);
        mn = fmaxf(mn, 0.0f);  // matches reference's clamp
        // wave-64 shuffle sum (tid<64 is exactly one wave)
        #pragma unroll
        for (int off = 32; off > 0; off >>= 1)
            mn += __shfl_down(mn, off, 64);
        if (tid == 0) ws[bid] = mn;
    }
}

__global__ __launch_bounds__(256)
void final_reduce_kernel(const float* __restrict__ ws, int n,
                         float* __restrict__ out, float inv_count) {
    __shared__ float sm[256];
    float ssum = 0.0f;
    for (int i = threadIdx.x; i < n; i += 256) ssum += ws[i];
    sm[threadIdx.x] = ssum;
    __syncthreads();
    #pragma unroll
    for (int off = 128; off > 0; off >>= 1) {
        if (threadIdx.x < off) sm[threadIdx.x] += sm[threadIdx.x + off];
        __syncthreads();
    }
    if (threadIdx.x == 0) out[0] = sm[0] * inv_count;
}

extern "C" void kernel_launch(void* const* d_in, const int* in_sizes, int n_in,
                              void* d_out, int out_size, void* d_ws, size_t ws_size,
                              hipStream_t stream) {
    const float* coord   = (const float*)d_in[0];
    const float* coord_t = (const float*)d_in[1];
    const float* Rm      = (const float*)d_in[2];
    const float* tv      = (const float*)d_in[3];

    const int B = in_sizes[2] / 9;                 // R is [B,3,3]
    const int S = in_sizes[0] / (3 * B);           // coord is [B*S,3]
    const int chunksPerSeg = S / SRC_PER_BLOCK;    // S=2048 -> 32
    const int nblocks = B * chunksPerSeg;          // 512

    float* ws = (float*)d_ws;
    float* out = (float*)d_out;

    const size_t smem = (size_t)S * 16 + THREADS * 4;

    nn_partial_kernel<<<nblocks, THREADS, smem, stream>>>(
        coord, coord_t, Rm, tv, ws, S, chunksPerSeg);

    final_reduce_kernel<<<1, 256, 0, stream>>>(
        ws, nblocks, out, 1.0f / ((float)B * (float)S));
}

// Round 2
// 17.898 us; speedup vs baseline: 1.3246x; 1.3246x over previous
//
#include <hip/hip_runtime.h>
#include <math.h>

// NN-MSE (one-directional Chamfer) loss, 3 stages:
//  k1: per (segment, 512-src chunk, 256-tgt slice) block -> per-source slice-min
//  k2: min over 8 target slices per source, sum per 256-source block
//  k3: sum 128 partials -> loss scalar
//
// Eval form: d2 = |s|^2 + min_m( |t_m|^2 - 2 s.t_m ); tile holds
// (-2x,-2y,-2z,|t|^2) so each eval is 3 FMA; |s|^2 folded per-source at end.
// Each lane owns P=8 transformed sources -> each broadcast ds_read_b128 feeds
// 8x2 evals (56 VALU ops), and 8 independent best[] chains give ILP.

#define THREADS 256
#define P 8
#define SRC_BLK 512      // sources per block = 64 lanes * P
#define TGT_BLK 256      // targets per block slice
#define WAVE_TGT 64      // targets per wave = TGT_BLK / 4 waves

__global__ __launch_bounds__(THREADS)
void nn_slice_kernel(const float* __restrict__ coord,
                     const float* __restrict__ coord_t,
                     const float* __restrict__ Rm,
                     const float* __restrict__ tv,
                     float* __restrict__ slice_min,   // [B][NTS][S]
                     int S, int NSC, int NTS) {
    __shared__ float4 tile[TGT_BLK];
    __shared__ float  part[THREADS][P + 1];   // +1 pad: conflict-free epilogue

    const int tid  = threadIdx.x;
    const int bid  = blockIdx.x;
    const int b    = bid / (NSC * NTS);
    const int rem  = bid - b * (NSC * NTS);
    const int sc   = rem / NTS;
    const int ts   = rem - sc * NTS;
    const int w    = tid >> 6;
    const int lane = tid & 63;

    // ---- stage target slice as (-2x,-2y,-2z,|t|^2) ----
    {
        const float* tb = coord_t + ((size_t)b * S + (size_t)ts * TGT_BLK) * 3;
        const int m = tid;                    // TGT_BLK == THREADS
        const float x = tb[3*m], y = tb[3*m+1], z = tb[3*m+2];
        tile[m] = make_float4(-2.f*x, -2.f*y, -2.f*z, x*x + y*y + z*z);
    }

    // ---- rigid transform params (block-uniform) ----
    const float* Rb = Rm + (size_t)b * 9;
    const float r00=Rb[0], r01=Rb[1], r02=Rb[2];
    const float r10=Rb[3], r11=Rb[4], r12=Rb[5];
    const float r20=Rb[6], r21=Rb[7], r22=Rb[8];
    const float t0=tv[3*b], t1=tv[3*b+1], t2=tv[3*b+2];

    // ---- load + transform this lane's 8 source points ----
    float TX[P], TY[P], TZ[P], SN[P], best[P];
    {
        const float4* g4 = reinterpret_cast<const float4*>(
            coord + ((size_t)b * S + (size_t)sc * SRC_BLK + lane * P) * 3);
        float f[3 * P];
        #pragma unroll
        for (int k = 0; k < (3 * P) / 4; ++k) {
            const float4 q = g4[k];
            f[4*k+0] = q.x; f[4*k+1] = q.y; f[4*k+2] = q.z; f[4*k+3] = q.w;
        }
        #pragma unroll
        for (int j = 0; j < P; ++j) {
            const float x = f[3*j], y = f[3*j+1], z = f[3*j+2];
            const float sx = __builtin_fmaf(r00,x,__builtin_fmaf(r01,y,__builtin_fmaf(r02,z,t0)));
            const float sy = __builtin_fmaf(r10,x,__builtin_fmaf(r11,y,__builtin_fmaf(r12,z,t1)));
            const float sz = __builtin_fmaf(r20,x,__builtin_fmaf(r21,y,__builtin_fmaf(r22,z,t2)));
            TX[j]=sx; TY[j]=sy; TZ[j]=sz;
            SN[j]=sx*sx + sy*sy + sz*sz;
            best[j] = 3.0e38f;
        }
    }

    __syncthreads();

    // ---- main loop: wave w scans its 64-target sub-slice, 2 targets/iter ----
    const int mbase = w * WAVE_TGT;
    #pragma unroll 4
    for (int it = 0; it < WAVE_TGT / 2; ++it) {
        const float4 p0 = tile[mbase + 2*it + 0];
        const float4 p1 = tile[mbase + 2*it + 1];
        #pragma unroll
        for (int j = 0; j < P; ++j) {
            const float v0 = __builtin_fmaf(p0.x,TX[j],__builtin_fmaf(p0.y,TY[j],__builtin_fmaf(p0.z,TZ[j],p0.w)));
            const float v1 = __builtin_fmaf(p1.x,TX[j],__builtin_fmaf(p1.y,TY[j],__builtin_fmaf(p1.z,TZ[j],p1.w)));
            best[j] = fminf(best[j], fminf(v0, v1));   // -> v_min3_f32
        }
    }

    // ---- fold |s|^2, combine across the 4 waves, write slice-min ----
    #pragma unroll
    for (int j = 0; j < P; ++j) part[tid][j] = best[j] + SN[j];
    __syncthreads();

    for (int s = tid; s < SRC_BLK; s += THREADS) {    // 2 iterations
        const int l = s >> 3;          // owning lane
        const int j = s & (P - 1);
        float mn = part[l][j];
        #pragma unroll
        for (int ww = 1; ww < 4; ++ww)
            mn = fminf(mn, part[ww * 64 + l][j]);
        const float d2 = fmaxf(mn, 0.0f);
        slice_min[((size_t)(b * NTS + ts)) * S + (size_t)sc * SRC_BLK + s] = d2;
    }
}

__global__ __launch_bounds__(256)
void combine_kernel(const float* __restrict__ slice_min,
                    float* __restrict__ partial,
                    int S, int NTS) {
    const int g = blockIdx.x * 256 + threadIdx.x;   // global source id
    const int b = g / S;
    const int n = g - b * S;
    const float* p = slice_min + ((size_t)b * NTS) * S + n;
    float mn = p[0];
    for (int ts = 1; ts < NTS; ++ts) mn = fminf(mn, p[(size_t)ts * S]);

    float v = mn;
    #pragma unroll
    for (int off = 32; off > 0; off >>= 1) v += __shfl_down(v, off, 64);
    __shared__ float wsum[4];
    if ((threadIdx.x & 63) == 0) wsum[threadIdx.x >> 6] = v;
    __syncthreads();
    if (threadIdx.x == 0)
        partial[blockIdx.x] = wsum[0] + wsum[1] + wsum[2] + wsum[3];
}

__global__ __launch_bounds__(128)
void final_kernel(const float* __restrict__ partial, int n,
                  float* __restrict__ out, float scale) {
    float v = (threadIdx.x < n) ? partial[threadIdx.x] : 0.0f;
    #pragma unroll
    for (int off = 32; off > 0; off >>= 1) v += __shfl_down(v, off, 64);
    __shared__ float sm[2];
    if ((threadIdx.x & 63) == 0) sm[threadIdx.x >> 6] = v;
    __syncthreads();
    if (threadIdx.x == 0) out[0] = (sm[0] + sm[1]) * scale;
}

extern "C" void kernel_launch(void* const* d_in, const int* in_sizes, int n_in,
                              void* d_out, int out_size, void* d_ws, size_t ws_size,
                              hipStream_t stream) {
    const float* coord   = (const float*)d_in[0];
    const float* coord_t = (const float*)d_in[1];
    const float* Rm      = (const float*)d_in[2];
    const float* tv      = (const float*)d_in[3];

    const int B = in_sizes[2] / 9;            // R is [B,3,3]
    const int S = in_sizes[0] / (3 * B);      // coord is [B*S,3]
    const int NSC = S / SRC_BLK;              // 4
    const int NTS = S / TGT_BLK;              // 8

    float* slice_min = (float*)d_ws;                      // B*NTS*S floats (1 MB)
    float* partial   = slice_min + (size_t)B * NTS * S;   // 128 floats
    float* out       = (float*)d_out;

    const int nblk1 = B * NSC * NTS;          // 512
    nn_slice_kernel<<<nblk1, THREADS, 0, stream>>>(
        coord, coord_t, Rm, tv, slice_min, S, NSC, NTS);

    const int nblk2 = (B * S) / 256;          // 128
    combine_kernel<<<nblk2, 256, 0, stream>>>(slice_min, partial, S, NTS);

    final_kernel<<<1, 128, 0, stream>>>(
        partial, nblk2, out, 1.0f / ((float)B * (float)S));
}

// Round 3
// 14.316 us; speedup vs baseline: 1.6560x; 1.2502x over previous
//
#include <hip/hip_runtime.h>
#include <math.h>

// NN-MSE (one-directional Chamfer) loss, 2 stages:
//  k1: per (segment, 128-src chunk) block of 512 threads -> full per-source
//      min over ALL S targets (8 waves split targets 8-way), block-sum -> ws
//  k2: sum 256 block partials -> loss scalar
//
// Eval form: d2 = |s|^2 + min_m( |t_m|^2 - 2 s.t_m ); LDS tile holds
// (-2x,-2y,-2z,|t|^2) so each eval is 3 FMA; |s|^2 folded per-source at end.
// Each lane owns P=2 sources; every broadcast ds_read_b128 feeds 2 evals with
// independent best[] chains (fminf pairs fuse to v_min3_f32).

#define THREADS 512      // 8 waves
#define NW 8
#define P 2
#define SRC_BLK 128      // 64 lanes * P

__global__ __launch_bounds__(THREADS)
void nn_full_kernel(const float* __restrict__ coord,
                    const float* __restrict__ coord_t,
                    const float* __restrict__ Rm,
                    const float* __restrict__ tv,
                    float* __restrict__ ws,
                    int S, int NSC) {
    extern __shared__ char smem_raw[];
    float4* tile = (float4*)smem_raw;                          // S float4
    float*  part = (float*)(smem_raw + (size_t)S * 16);        // NW*64*P
    float*  wsum = part + NW * 64 * P;                         // 2 floats

    const int tid  = threadIdx.x;
    const int bid  = blockIdx.x;
    const int b    = bid / NSC;
    const int sc   = bid - b * NSC;
    const int w    = tid >> 6;
    const int lane = tid & 63;

    // ---- stage ALL S targets as (-2x,-2y,-2z,|t|^2); 4 points/thread ----
    {
        const float* tb = coord_t + (size_t)b * S * 3;
        for (int base = tid * 4; base < S; base += THREADS * 4) {
            const float4* g4 = reinterpret_cast<const float4*>(tb + (size_t)base * 3);
            const float4 q0 = g4[0], q1 = g4[1], q2 = g4[2];
            const float px[4] = {q0.x, q0.w, q1.z, q2.y};
            const float py[4] = {q0.y, q1.x, q1.w, q2.z};
            const float pz[4] = {q0.z, q1.y, q2.x, q2.w};
            #pragma unroll
            for (int k = 0; k < 4; ++k) {
                const float x = px[k], y = py[k], z = pz[k];
                tile[base + k] = make_float4(-2.f*x, -2.f*y, -2.f*z,
                                             x*x + y*y + z*z);
            }
        }
    }

    // ---- rigid transform params (block-uniform, scalar regs) ----
    const float* Rb = Rm + (size_t)b * 9;
    const float r00=Rb[0], r01=Rb[1], r02=Rb[2];
    const float r10=Rb[3], r11=Rb[4], r12=Rb[5];
    const float r20=Rb[6], r21=Rb[7], r22=Rb[8];
    const float t0=tv[3*b], t1=tv[3*b+1], t2=tv[3*b+2];

    // ---- this lane's P=2 source points, transformed ----
    float TX[P], TY[P], TZ[P], SN[P], best[P];
    {
        const float* sp = coord + ((size_t)b * S + (size_t)sc * SRC_BLK + lane * P) * 3;
        #pragma unroll
        for (int j = 0; j < P; ++j) {
            const float x = sp[3*j], y = sp[3*j+1], z = sp[3*j+2];
            const float sx = __builtin_fmaf(r00,x,__builtin_fmaf(r01,y,__builtin_fmaf(r02,z,t0)));
            const float sy = __builtin_fmaf(r10,x,__builtin_fmaf(r11,y,__builtin_fmaf(r12,z,t1)));
            const float sz = __builtin_fmaf(r20,x,__builtin_fmaf(r21,y,__builtin_fmaf(r22,z,t2)));
            TX[j]=sx; TY[j]=sy; TZ[j]=sz;
            SN[j]=sx*sx + sy*sy + sz*sz;
            best[j] = 3.0e38f;
        }
    }

    __syncthreads();

    // ---- main loop: wave w scans its S/NW targets, 4 per iteration ----
    const int mPer  = S / NW;
    const int mbase = w * mPer;
    #pragma unroll 2
    for (int it = 0; it < mPer / 4; ++it) {
        const float4 p0 = tile[mbase + 4*it + 0];
        const float4 p1 = tile[mbase + 4*it + 1];
        const float4 p2 = tile[mbase + 4*it + 2];
        const float4 p3 = tile[mbase + 4*it + 3];
        #pragma unroll
        for (int j = 0; j < P; ++j) {
            const float v0 = __builtin_fmaf(p0.x,TX[j],__builtin_fmaf(p0.y,TY[j],__builtin_fmaf(p0.z,TZ[j],p0.w)));
            const float v1 = __builtin_fmaf(p1.x,TX[j],__builtin_fmaf(p1.y,TY[j],__builtin_fmaf(p1.z,TZ[j],p1.w)));
            const float v2 = __builtin_fmaf(p2.x,TX[j],__builtin_fmaf(p2.y,TY[j],__builtin_fmaf(p2.z,TZ[j],p2.w)));
            const float v3 = __builtin_fmaf(p3.x,TX[j],__builtin_fmaf(p3.y,TY[j],__builtin_fmaf(p3.z,TZ[j],p3.w)));
            best[j] = fminf(fminf(best[j], v0), v1);   // v_min3
            best[j] = fminf(fminf(best[j], v2), v3);   // v_min3
        }
    }

    // ---- fold |s|^2; min across 8 waves; clamp; block sum ----
    #pragma unroll
    for (int j = 0; j < P; ++j)
        part[(w * 64 + lane) * P + j] = best[j] + SN[j];
    __syncthreads();

    float v = 0.0f;
    if (tid < SRC_BLK) {
        // thread s reads part[ww*128 + s] -> stride-1, conflict-free
        float mn = part[tid];
        #pragma unroll
        for (int ww = 1; ww < NW; ++ww)
            mn = fminf(mn, part[ww * SRC_BLK + tid]);
        v = fmaxf(mn, 0.0f);
    }
    if (tid < 128) {
        #pragma unroll
        for (int off = 32; off > 0; off >>= 1) v += __shfl_down(v, off, 64);
        if ((tid & 63) == 0) wsum[tid >> 6] = v;
    }
    __syncthreads();
    if (tid == 0) ws[bid] = wsum[0] + wsum[1];
}

__global__ __launch_bounds__(256)
void final_kernel(const float* __restrict__ partial, int n,
                  float* __restrict__ out, float scale) {
    float v = (threadIdx.x < n) ? partial[threadIdx.x] : 0.0f;
    #pragma unroll
    for (int off = 32; off > 0; off >>= 1) v += __shfl_down(v, off, 64);
    __shared__ float sm[4];
    if ((threadIdx.x & 63) == 0) sm[threadIdx.x >> 6] = v;
    __syncthreads();
    if (threadIdx.x == 0) out[0] = (sm[0] + sm[1] + sm[2] + sm[3]) * scale;
}

extern "C" void kernel_launch(void* const* d_in, const int* in_sizes, int n_in,
                              void* d_out, int out_size, void* d_ws, size_t ws_size,
                              hipStream_t stream) {
    const float* coord   = (const float*)d_in[0];
    const float* coord_t = (const float*)d_in[1];
    const float* Rm      = (const float*)d_in[2];
    const float* tv      = (const float*)d_in[3];

    const int B = in_sizes[2] / 9;            // R is [B,3,3]
    const int S = in_sizes[0] / (3 * B);      // coord is [B*S,3]
    const int NSC = S / SRC_BLK;              // 16
    const int nblk = B * NSC;                 // 256

    float* ws  = (float*)d_ws;
    float* out = (float*)d_out;

    const size_t smem = (size_t)S * 16 + NW * 64 * P * 4 + 2 * 4;

    nn_full_kernel<<<nblk, THREADS, smem, stream>>>(
        coord, coord_t, Rm, tv, ws, S, NSC);

    final_kernel<<<1, 256, 0, stream>>>(
        ws, nblk, out, 1.0f / ((float)B * (float)S));
}